// Round 7
// baseline (1960.251 us; speedup 1.0000x reference)
//
#include <hip/hip_runtime.h>
#include <math.h>

constexpr int Bsz = 64;
constexpr int Lsz = 2048;
constexpr int Hsz = 128;
constexpr int Vsz = 32000;
constexpr int TOK = Bsz * Lsz;

typedef float f2v __attribute__((ext_vector_type(2)));

__device__ __forceinline__ f2v pkfma(f2v a, f2v b, f2v c) {
    return __builtin_elementwise_fma(a, b, c);
}

// ---------------- DPP add helper: v += dpp_move(v) --------------------------
template<int CTRL, int RM>
__device__ __forceinline__ float dppadd(float v) {
    int x = __builtin_amdgcn_update_dpp(0, __float_as_int(v), CTRL, RM, 0xf, false);
    return v + __int_as_float(x);
}

// ---------------- generic transpose: in[R][C] -> out[C][R] ----------------
__global__ void k_tr(const float* __restrict__ in, float* __restrict__ out, int R, int C) {
    __shared__ float tile[32][33];
    int bc = blockIdx.x * 32, br = blockIdx.y * 32;
    int tx = threadIdx.x & 31, ty = threadIdx.x >> 5;  // 256 threads
#pragma unroll
    for (int i = 0; i < 4; i++) {
        int r = br + ty + 8 * i, c = bc + tx;
        if (r < R && c < C) tile[ty + 8 * i][tx] = in[(size_t)r * C + c];
    }
    __syncthreads();
#pragma unroll
    for (int i = 0; i < 4; i++) {
        int c = bc + ty + 8 * i, r = br + tx;
        if (c < C && r < R) out[(size_t)c * R + r] = tile[tx][ty + 8 * i];
    }
}

// ---------------- fused embed + FF1 + FF2 + residual + LN + kp + norms ----
__global__ __launch_bounds__(256, 2)
void k_ff(const int* __restrict__ seq, const float* __restrict__ embed,
          const float* __restrict__ w1T, const float* __restrict__ b1,
          const float* __restrict__ w2T, const float* __restrict__ b2,
          const float* __restrict__ ln_g, const float* __restrict__ ln_b,
          const float* __restrict__ kpT,
          float* __restrict__ k_all, float* __restrict__ norms)
{
    __shared__ float su[256 * 65];
    const int tid = threadIdx.x;
    const int tok = blockIdx.x * 256 + tid;
    const float* hrow = embed + (size_t)seq[tok] * Hsz;
    float* myl = su + tid * 65;

    float f[Hsz];
#pragma unroll
    for (int n = 0; n < Hsz; n++) f[n] = b2[n];

    for (int p = 0; p < 4; p++) {
        float u[64];
#pragma unroll
        for (int n = 0; n < 64; n++) u[n] = b1[p * 64 + n];
        const float* w1p = w1T + p * 64;
        for (int k = 0; k < Hsz; k += 4) {
            float4 a = *(const float4*)(hrow + k);
            const float* wr = w1p + (size_t)k * 256;
#pragma unroll
            for (int n = 0; n < 64; n++) u[n] = fmaf(a.x, wr[n], u[n]);
            wr += 256;
#pragma unroll
            for (int n = 0; n < 64; n++) u[n] = fmaf(a.y, wr[n], u[n]);
            wr += 256;
#pragma unroll
            for (int n = 0; n < 64; n++) u[n] = fmaf(a.z, wr[n], u[n]);
            wr += 256;
#pragma unroll
            for (int n = 0; n < 64; n++) u[n] = fmaf(a.w, wr[n], u[n]);
        }
#pragma unroll
        for (int n = 0; n < 64; n++) myl[n] = fmaxf(u[n], 0.0f);
        const float* w2p = w2T + (size_t)(p * 64) * Hsz;
        for (int kk = 0; kk < 64; kk++) {
            float uv = myl[kk];
            const float* wr = w2p + (size_t)kk * Hsz;
#pragma unroll
            for (int n = 0; n < Hsz; n++) f[n] = fmaf(uv, wr[n], f[n]);
        }
    }

    float m0 = 0, m1 = 0, m2 = 0, m3 = 0;
#pragma unroll
    for (int n = 0; n < Hsz; n += 4) {
        float4 hv = *(const float4*)(hrow + n);
        f[n] += hv.x; f[n + 1] += hv.y; f[n + 2] += hv.z; f[n + 3] += hv.w;
        m0 += f[n]; m1 += f[n + 1]; m2 += f[n + 2]; m3 += f[n + 3];
    }
    float mu = (m0 + m1 + m2 + m3) * (1.0f / Hsz);
    float v0 = 0, v1 = 0, v2 = 0, v3 = 0;
#pragma unroll
    for (int n = 0; n < Hsz; n += 4) {
        float d0 = f[n] - mu, d1 = f[n + 1] - mu, d2 = f[n + 2] - mu, d3 = f[n + 3] - mu;
        v0 = fmaf(d0, d0, v0); v1 = fmaf(d1, d1, v1);
        v2 = fmaf(d2, d2, v2); v3 = fmaf(d3, d3, v3);
    }
    float var = (v0 + v1 + v2 + v3) * (1.0f / Hsz);
    float rs = 1.0f / sqrtf(var + 1e-5f);
#pragma unroll
    for (int n = 0; n < Hsz; n++) f[n] = (f[n] - mu) * rs * ln_g[n] + ln_b[n];

    float nrm2 = 0.0f;
    float* kout = k_all + (size_t)tok * Hsz;
    for (int p2 = 0; p2 < 2; p2++) {
        float acc[64];
#pragma unroll
        for (int n = 0; n < 64; n++) acc[n] = 0.0f;
        for (int kh = 0; kh < 2; kh++) {
#pragma unroll
            for (int n = 0; n < 64; n++) myl[n] = f[kh * 64 + n];
            const float* kpp = kpT + (size_t)(kh * 64) * Hsz + p2 * 64;
            for (int k = 0; k < 64; k++) {
                float yv = myl[k];
                const float* wr = kpp + (size_t)k * Hsz;
#pragma unroll
                for (int n = 0; n < 64; n++) acc[n] = fmaf(yv, wr[n], acc[n]);
            }
        }
#pragma unroll
        for (int n = 0; n < 64; n++) nrm2 = fmaf(acc[n], acc[n], nrm2);
#pragma unroll
        for (int n = 0; n < 64; n += 4) {
            float4 vv; vv.x = acc[n]; vv.y = acc[n + 1]; vv.z = acc[n + 2]; vv.w = acc[n + 3];
            *(float4*)(kout + p2 * 64 + n) = vv;
        }
    }
    norms[tok] = nrm2;
}

// ------- per-row meta: {nrm2, rn, dot(k_t,k_t+1), dot(k_t,k_t+2)} ---------
__global__ void k_meta(const float* __restrict__ k_all, const float* __restrict__ norms,
                       float4* __restrict__ meta)
{
    int t = blockIdx.x * 256 + threadIdx.x;   // 0..TOK-1
    int i = t & (Lsz - 1);
    float nrm2 = norms[t];
    float rn = 1.0f / fmaxf(sqrtf(nrm2), 1e-12f);
    float dot1 = 0.f, dot2 = 0.f;
    const float4* r0 = (const float4*)(k_all + (size_t)t * Hsz);
    if (i < Lsz - 1) {
        const float4* r1 = (const float4*)(k_all + (size_t)(t + 1) * Hsz);
        float d0 = 0, d1 = 0, d2 = 0, d3 = 0;
#pragma unroll
        for (int q = 0; q < 32; q++) {
            float4 x = r0[q], y = r1[q];
            d0 = fmaf(x.x, y.x, d0); d1 = fmaf(x.y, y.y, d1);
            d2 = fmaf(x.z, y.z, d2); d3 = fmaf(x.w, y.w, d3);
        }
        dot1 = (d0 + d1) + (d2 + d3);
    }
    if (i < Lsz - 2) {
        const float4* r2 = (const float4*)(k_all + (size_t)(t + 2) * Hsz);
        float d0 = 0, d1 = 0, d2 = 0, d3 = 0;
#pragma unroll
        for (int q = 0; q < 32; q++) {
            float4 x = r0[q], y = r2[q];
            d0 = fmaf(x.x, y.x, d0); d1 = fmaf(x.y, y.y, d1);
            d2 = fmaf(x.z, y.z, d2); d3 = fmaf(x.w, y.w, d3);
        }
        dot2 = (d0 + d1) + (d2 + d3);
    }
    meta[t] = make_float4(nrm2, rn, dot1, dot2);
}

// ---------------- lag-2 look-ahead gated rank-1 scan ----------------------
// vp_t = A_t + c1*r_{t-1} + c2*r_{t-2},  A_t = (M_{t-3} k_t) * rn_t
// c1 = g_{t-1} d1(t-1) rn_{t-1} rn_t ; c2 = g_{t-2} d2(t-2) rn_{t-2} rn_t.
// M-update lags 2 steps (gate known); matvec runs 1 body ahead on lag-3 M.
// LDS: [slot][ch][68] -> ch0/ch1 chunks on disjoint bank groups (no conflicts).
__global__ __launch_bounds__(256, 1)
void k_scan(const float* __restrict__ k_all, const float4* __restrict__ meta,
            float* __restrict__ readv)
{
    __shared__ float lds[8 * 136];      // 8-slot ring: row r lives in slot r&7
    __shared__ float4 part4[2];
    const int b = blockIdx.x, tid = threadIdx.x;
    const int row = tid >> 1, ch = tid & 1, lane = tid & 63, w = tid >> 6;
    const float* kb = k_all + (size_t)b * Lsz * Hsz;
    const float4* mb = meta + (size_t)b * Lsz;

    const int stoff = (lane >= 32) ? (68 + 2 * lane - 64) : (2 * lane);
    const int chbase = ch * 68;
    const int kelo = (row >> 6) * 68 + (row & 63);

    f2v M2[32];
#pragma unroll
    for (int j = 0; j < 32; j++) M2[j] = f2v{0.f, 0.f};

    // ---- prologue: stage rows 0..4, preload glob rows 5,6, fill mvA(row 1)
    for (int t0 = 0; t0 < 5; t0++) {
        float2 v = *(const float2*)(kb + (size_t)t0 * Hsz + 2 * lane);
        *(float2*)(lds + t0 * 136 + stoff) = v;
    }
    float2 kgA = *(const float2*)(kb + (size_t)5 * Hsz + 2 * lane);
    float2 kgB = *(const float2*)(kb + (size_t)6 * Hsz + 2 * lane);
    float4 mvA[16], mvB[16];
    {
        const float4* pF = (const float4*)(lds + 1 * 136 + chbase);
#pragma unroll
        for (int q = 0; q < 16; q++) mvA[q] = pF[q];
    }
    float4 m0 = mb[0], m1 = mb[1], m2 = mb[2];
    __syncthreads();
    float kel_cur = lds[0 * 136 + kelo];

    float a_cur = 0.f, c1_cur = 0.f, c2_cur = 0.f, c2_pipe = 0.f;
    float r1el = 0.f, r2el = 0.f, uc1 = 0.f, uc2 = 0.f;
    bool gate1 = false, gate2 = false;

    auto body = [&](int t, float4 (&mvUse)[16], float4 (&mvFill)[16], float2& kgreg) {
        const int sW = (t + 5) & 7, sU = (t - 2) & 7, sMv = (t + 2) & 7, sK = (t + 1) & 7;
        const int slot = t & 1;

        // issue update-chunk reads (row t-2; garbage pre-t=2, gated off)
        float4 uT[16];
        {
            const float4* pU = (const float4*)(lds + sU * 136 + chbase);
#pragma unroll
            for (int q = 0; q < 16; q++) uT[q] = pU[q];
        }
        // issue mv-fill reads for NEXT body (row t+2)
        {
            const float4* pF = (const float4*)(lds + sMv * 136 + chbase);
#pragma unroll
            for (int q = 0; q < 16; q++) mvFill[q] = pF[q];
        }

        // ---- gate chain: residual + DPP wave reduce ----
        float rel = kel_cur - a_cur;
        rel = fmaf(-c1_cur, r1el, rel);
        rel = fmaf(-c2_cur, r2el, rel);
        float s = rel * rel;
        s = dppadd<0xB1, 0xf>(s);
        s = dppadd<0x4E, 0xf>(s);
        s = dppadd<0x141, 0xf>(s);
        s = dppadd<0x140, 0xf>(s);
        s = dppadd<0x142, 0xa>(s);
        s = dppadd<0x143, 0xc>(s);
        if (lane == 63) ((float*)&part4[slot])[w] = s;

        // ---- stage row t+5 + reload row t+7 (off critical path) ----
        *(float2*)(lds + sW * 136 + stoff) = kgreg;
        {
            int tl = t + 7; if (tl > Lsz - 1) tl = Lsz - 1;
            kgreg = *(const float2*)(kb + (size_t)tl * Hsz + 2 * lane);
        }

        // ---- lagged update u_{t-2} (gate known 2 bodies ago) ----
        if (gate2) {
            f2v c = {uc2, uc2};
#pragma unroll
            for (int q = 0; q < 16; q++) {
                float4 kv = uT[q];
                M2[2 * q]     = pkfma(c, f2v{kv.x, kv.y}, M2[2 * q]);
                M2[2 * q + 1] = pkfma(c, f2v{kv.z, kv.w}, M2[2 * q + 1]);
            }
        }
        // ---- matvec A_{t+1} = M_{t-2} * k_{t+1} (regs filled last body) ----
        f2v a20 = {0.f, 0.f}, a21 = {0.f, 0.f}, a22 = {0.f, 0.f}, a23 = {0.f, 0.f};
#pragma unroll
        for (int q = 0; q < 16; q += 2) {
            float4 kv0 = mvUse[q], kv1 = mvUse[q + 1];
            a20 = pkfma(M2[2 * q],     f2v{kv0.x, kv0.y}, a20);
            a21 = pkfma(M2[2 * q + 1], f2v{kv0.z, kv0.w}, a21);
            a22 = pkfma(M2[2 * q + 2], f2v{kv1.x, kv1.y}, a22);
            a23 = pkfma(M2[2 * q + 3], f2v{kv1.z, kv1.w}, a23);
        }
        f2v a2 = (a20 + a21) + (a22 + a23);
        float an = a2.x + a2.y;
        an = dppadd<0xB1, 0xf>(an);          // full-row dot (both ch lanes)

        __syncthreads();
        float4 p = part4[slot];
        float kel_next = lds[sK * 136 + kelo];
        float4 m3;
        { int tm = t + 3; if (tm > Lsz - 1) tm = Lsz - 1; m3 = mb[tm]; }
        float energy = (p.x + p.y + p.z + p.w) * 3.0517578125e-05f /* 0.5/16384 */
                       * m0.x * m0.y * m0.y;
        bool g = energy >= 0.4f;             // block-uniform

        // ---- scalar pipeline shifts ----
        a_cur = an * m1.y;                             // A_{t+1}
        c1_cur = g ? m0.z * m0.y * m1.y : 0.f;         // for body t+1
        c2_cur = c2_pipe;                              // set at body t-1, for t+1
        c2_pipe = g ? m0.w * m0.y * m2.y : 0.f;        // for body t+2
        uc2 = uc1; uc1 = g ? rel * m0.y : 0.f;
        gate2 = gate1; gate1 = g;
        r2el = r1el; r1el = rel;
        kel_cur = kel_next;
        m0 = m1; m1 = m2; m2 = m3;
    };

    for (int t = 0; t < Lsz - 2; t += 2) {   // bodies 0..2045
        body(t,     mvA, mvB, kgA);
        body(t + 1, mvB, mvA, kgB);
    }
    body(Lsz - 2, mvA, mvB, kgA);            // body 2046

    // ---- epilogue: pending updates u_2045 (uc2) and u_2046 (uc1) ----
    if (gate2) {
        const float4* pU = (const float4*)(lds + ((Lsz - 3) & 7) * 136 + chbase);
        f2v c = {uc2, uc2};
#pragma unroll
        for (int q = 0; q < 16; q++) {
            float4 kv = pU[q];
            M2[2 * q]     = pkfma(c, f2v{kv.x, kv.y}, M2[2 * q]);
            M2[2 * q + 1] = pkfma(c, f2v{kv.z, kv.w}, M2[2 * q + 1]);
        }
    }
    if (gate1) {
        const float4* pU = (const float4*)(lds + ((Lsz - 2) & 7) * 136 + chbase);
        f2v c = {uc1, uc1};
#pragma unroll
        for (int q = 0; q < 16; q++) {
            float4 kv = pU[q];
            M2[2 * q]     = pkfma(c, f2v{kv.x, kv.y}, M2[2 * q]);
            M2[2 * q + 1] = pkfma(c, f2v{kv.z, kv.w}, M2[2 * q + 1]);
        }
    }
    {   // read = M_2046 . q  (raw q = row 2047, slot 7)
        const float4* pQ = (const float4*)(lds + ((Lsz - 1) & 7) * 136 + chbase);
        f2v a20 = {0.f, 0.f}, a21 = {0.f, 0.f};
#pragma unroll
        for (int q = 0; q < 16; q++) {
            float4 kv = pQ[q];
            a20 = pkfma(M2[2 * q],     f2v{kv.x, kv.y}, a20);
            a21 = pkfma(M2[2 * q + 1], f2v{kv.z, kv.w}, a21);
        }
        f2v a2 = a20 + a21;
        float an = a2.x + a2.y;
        an = dppadd<0xB1, 0xf>(an);
        if (ch == 0) readv[b * Hsz + row] = an;
    }
}

// ---------------- r2T[n][b] = read[b] @ rp_w.T + rp_b -----------------
__global__ void k_r2(const float* __restrict__ readv, const float* __restrict__ rp_w,
                     const float* __restrict__ rp_b, float* __restrict__ r2T)
{
    int b = blockIdx.x, n = threadIdx.x;
    const float* rr = readv + b * Hsz;
    const float* wr = rp_w + (size_t)n * Hsz;
    float acc = rp_b[n];
    for (int k = 0; k < Hsz; k++) acc = fmaf(rr[k], wr[k], acc);
    r2T[(size_t)n * Bsz + b] = acc;
}

// ---------------- out[b][v] = r2[b] . out_w[v] + out_b[v] -----------------
__global__ __launch_bounds__(256, 4)
void k_out(const float* __restrict__ owT, const float* __restrict__ r2T,
           const float* __restrict__ outb, float* __restrict__ outp)
{
    int v = blockIdx.x * 256 + threadIdx.x;
    float ob = outb[v];
    float acc[Bsz];
#pragma unroll
    for (int b = 0; b < Bsz; b++) acc[b] = ob;
    for (int k = 0; k < Hsz; k++) {
        float wv = owT[(size_t)k * Vsz + v];
        const float* rr = r2T + k * Bsz;
#pragma unroll
        for (int b = 0; b < Bsz; b++) acc[b] = fmaf(wv, rr[b], acc[b]);
    }
#pragma unroll
    for (int b = 0; b < Bsz; b++) outp[(size_t)b * Vsz + v] = acc[b];
}

extern "C" void kernel_launch(void* const* d_in, const int* in_sizes, int n_in,
                              void* d_out, int out_size, void* d_ws, size_t ws_size,
                              hipStream_t stream)
{
    const int*   seq    = (const int*)  d_in[0];
    const float* embedW = (const float*)d_in[1];
    const float* ff_w1  = (const float*)d_in[2];
    const float* ff_b1  = (const float*)d_in[3];
    const float* ff_w2  = (const float*)d_in[4];
    const float* ff_b2  = (const float*)d_in[5];
    const float* ln_g   = (const float*)d_in[6];
    const float* ln_b   = (const float*)d_in[7];
    const float* kp_w   = (const float*)d_in[8];
    const float* rp_w   = (const float*)d_in[9];
    const float* rp_b   = (const float*)d_in[10];
    const float* out_w  = (const float*)d_in[11];
    const float* out_b  = (const float*)d_in[12];
    float* out = (float*)d_out;

    float* ws    = (float*)d_ws;
    float* k_all = ws;                                   // 16,777,216 f
    float* owT   = k_all + (size_t)TOK * Hsz;            //  4,096,000 f
    float* w1T   = owT   + (size_t)Hsz * Vsz;            // 32768
    float* w2T   = w1T   + 32768;                        // 32768
    float* kpT   = w2T   + 32768;                        // 16384
    float* norms = kpT   + 16384;                        // TOK
    float* metaf = norms + TOK;                          // 4*TOK (float4, 16B-aligned)
    float* readv = metaf + 4 * (size_t)TOK;              // B*H
    float* r2T   = readv + Bsz * Hsz;                    // H*B
    float4* meta = (float4*)metaf;

    k_tr<<<dim3(4, 8),    dim3(256), 0, stream>>>(ff_w1, w1T, 256, 128);
    k_tr<<<dim3(8, 4),    dim3(256), 0, stream>>>(ff_w2, w2T, 128, 256);
    k_tr<<<dim3(4, 4),    dim3(256), 0, stream>>>(kp_w,  kpT, 128, 128);
    k_tr<<<dim3(4, 1000), dim3(256), 0, stream>>>(out_w, owT, Vsz, 128);

    k_ff<<<dim3(TOK / 256), dim3(256), 0, stream>>>(
        seq, embedW, w1T, ff_b1, w2T, ff_b2, ln_g, ln_b, kpT, k_all, norms);

    k_meta<<<dim3(TOK / 256), dim3(256), 0, stream>>>(k_all, norms, meta);

    k_scan<<<dim3(Bsz), dim3(256), 0, stream>>>(k_all, meta, readv);

    k_r2<<<dim3(Bsz), dim3(128), 0, stream>>>(readv, rp_w, rp_b, r2T);

    k_out<<<dim3(Vsz / 256), dim3(256), 0, stream>>>(owT, r2T, out_b, out);
}

// Round 8
// 1687.775 us; speedup vs baseline: 1.1614x; 1.1614x over previous
//
#include <hip/hip_runtime.h>
#include <math.h>

constexpr int Bsz = 64;
constexpr int Lsz = 2048;
constexpr int Hsz = 128;
constexpr int Vsz = 32000;
constexpr int TOK = Bsz * Lsz;

typedef float f2v __attribute__((ext_vector_type(2)));

__device__ __forceinline__ f2v pkfma(f2v a, f2v b, f2v c) {
    return __builtin_elementwise_fma(a, b, c);
}

// ---------------- DPP add helper: v += dpp_move(v) --------------------------
template<int CTRL, int RM>
__device__ __forceinline__ float dppadd(float v) {
    int x = __builtin_amdgcn_update_dpp(0, __float_as_int(v), CTRL, RM, 0xf, false);
    return v + __int_as_float(x);
}

// ---------------- generic transpose: in[R][C] -> out[C][R] ----------------
__global__ void k_tr(const float* __restrict__ in, float* __restrict__ out, int R, int C) {
    __shared__ float tile[32][33];
    int bc = blockIdx.x * 32, br = blockIdx.y * 32;
    int tx = threadIdx.x & 31, ty = threadIdx.x >> 5;  // 256 threads
#pragma unroll
    for (int i = 0; i < 4; i++) {
        int r = br + ty + 8 * i, c = bc + tx;
        if (r < R && c < C) tile[ty + 8 * i][tx] = in[(size_t)r * C + c];
    }
    __syncthreads();
#pragma unroll
    for (int i = 0; i < 4; i++) {
        int c = bc + ty + 8 * i, r = br + tx;
        if (c < C && r < R) out[(size_t)c * R + r] = tile[tx][ty + 8 * i];
    }
}

// ---------------- fused embed + FF1 + FF2 + residual + LN + kp + norms ----
__global__ __launch_bounds__(256, 2)
void k_ff(const int* __restrict__ seq, const float* __restrict__ embed,
          const float* __restrict__ w1T, const float* __restrict__ b1,
          const float* __restrict__ w2T, const float* __restrict__ b2,
          const float* __restrict__ ln_g, const float* __restrict__ ln_b,
          const float* __restrict__ kpT,
          float* __restrict__ k_all, float* __restrict__ norms)
{
    __shared__ float su[256 * 65];
    const int tid = threadIdx.x;
    const int tok = blockIdx.x * 256 + tid;
    const float* hrow = embed + (size_t)seq[tok] * Hsz;
    float* myl = su + tid * 65;

    float f[Hsz];
#pragma unroll
    for (int n = 0; n < Hsz; n++) f[n] = b2[n];

    for (int p = 0; p < 4; p++) {
        float u[64];
#pragma unroll
        for (int n = 0; n < 64; n++) u[n] = b1[p * 64 + n];
        const float* w1p = w1T + p * 64;
        for (int k = 0; k < Hsz; k += 4) {
            float4 a = *(const float4*)(hrow + k);
            const float* wr = w1p + (size_t)k * 256;
#pragma unroll
            for (int n = 0; n < 64; n++) u[n] = fmaf(a.x, wr[n], u[n]);
            wr += 256;
#pragma unroll
            for (int n = 0; n < 64; n++) u[n] = fmaf(a.y, wr[n], u[n]);
            wr += 256;
#pragma unroll
            for (int n = 0; n < 64; n++) u[n] = fmaf(a.z, wr[n], u[n]);
            wr += 256;
#pragma unroll
            for (int n = 0; n < 64; n++) u[n] = fmaf(a.w, wr[n], u[n]);
        }
#pragma unroll
        for (int n = 0; n < 64; n++) myl[n] = fmaxf(u[n], 0.0f);
        const float* w2p = w2T + (size_t)(p * 64) * Hsz;
        for (int kk = 0; kk < 64; kk++) {
            float uv = myl[kk];
            const float* wr = w2p + (size_t)kk * Hsz;
#pragma unroll
            for (int n = 0; n < Hsz; n++) f[n] = fmaf(uv, wr[n], f[n]);
        }
    }

    float m0 = 0, m1 = 0, m2 = 0, m3 = 0;
#pragma unroll
    for (int n = 0; n < Hsz; n += 4) {
        float4 hv = *(const float4*)(hrow + n);
        f[n] += hv.x; f[n + 1] += hv.y; f[n + 2] += hv.z; f[n + 3] += hv.w;
        m0 += f[n]; m1 += f[n + 1]; m2 += f[n + 2]; m3 += f[n + 3];
    }
    float mu = (m0 + m1 + m2 + m3) * (1.0f / Hsz);
    float v0 = 0, v1 = 0, v2 = 0, v3 = 0;
#pragma unroll
    for (int n = 0; n < Hsz; n += 4) {
        float d0 = f[n] - mu, d1 = f[n + 1] - mu, d2 = f[n + 2] - mu, d3 = f[n + 3] - mu;
        v0 = fmaf(d0, d0, v0); v1 = fmaf(d1, d1, v1);
        v2 = fmaf(d2, d2, v2); v3 = fmaf(d3, d3, v3);
    }
    float var = (v0 + v1 + v2 + v3) * (1.0f / Hsz);
    float rs = 1.0f / sqrtf(var + 1e-5f);
#pragma unroll
    for (int n = 0; n < Hsz; n++) f[n] = (f[n] - mu) * rs * ln_g[n] + ln_b[n];

    float nrm2 = 0.0f;
    float* kout = k_all + (size_t)tok * Hsz;
    for (int p2 = 0; p2 < 2; p2++) {
        float acc[64];
#pragma unroll
        for (int n = 0; n < 64; n++) acc[n] = 0.0f;
        for (int kh = 0; kh < 2; kh++) {
#pragma unroll
            for (int n = 0; n < 64; n++) myl[n] = f[kh * 64 + n];
            const float* kpp = kpT + (size_t)(kh * 64) * Hsz + p2 * 64;
            for (int k = 0; k < 64; k++) {
                float yv = myl[k];
                const float* wr = kpp + (size_t)k * Hsz;
#pragma unroll
                for (int n = 0; n < 64; n++) acc[n] = fmaf(yv, wr[n], acc[n]);
            }
        }
#pragma unroll
        for (int n = 0; n < 64; n++) nrm2 = fmaf(acc[n], acc[n], nrm2);
#pragma unroll
        for (int n = 0; n < 64; n += 4) {
            float4 vv; vv.x = acc[n]; vv.y = acc[n + 1]; vv.z = acc[n + 2]; vv.w = acc[n + 3];
            *(float4*)(kout + p2 * 64 + n) = vv;
        }
    }
    norms[tok] = nrm2;
}

// ------- per-row meta: {nrm2, rn, dot(k_t,k_t+1), dot(k_t,k_t+2)} ---------
__global__ void k_meta(const float* __restrict__ k_all, const float* __restrict__ norms,
                       float4* __restrict__ meta)
{
    int t = blockIdx.x * 256 + threadIdx.x;   // 0..TOK-1
    int i = t & (Lsz - 1);
    float nrm2 = norms[t];
    float rn = 1.0f / fmaxf(sqrtf(nrm2), 1e-12f);
    float dot1 = 0.f, dot2 = 0.f;
    const float4* r0 = (const float4*)(k_all + (size_t)t * Hsz);
    if (i < Lsz - 1) {
        const float4* r1 = (const float4*)(k_all + (size_t)(t + 1) * Hsz);
        float d0 = 0, d1 = 0, d2 = 0, d3 = 0;
#pragma unroll
        for (int q = 0; q < 32; q++) {
            float4 x = r0[q], y = r1[q];
            d0 = fmaf(x.x, y.x, d0); d1 = fmaf(x.y, y.y, d1);
            d2 = fmaf(x.z, y.z, d2); d3 = fmaf(x.w, y.w, d3);
        }
        dot1 = (d0 + d1) + (d2 + d3);
    }
    if (i < Lsz - 2) {
        const float4* r2 = (const float4*)(k_all + (size_t)(t + 2) * Hsz);
        float d0 = 0, d1 = 0, d2 = 0, d3 = 0;
#pragma unroll
        for (int q = 0; q < 32; q++) {
            float4 x = r0[q], y = r2[q];
            d0 = fmaf(x.x, y.x, d0); d1 = fmaf(x.y, y.y, d1);
            d2 = fmaf(x.z, y.z, d2); d3 = fmaf(x.w, y.w, d3);
        }
        dot2 = (d0 + d1) + (d2 + d3);
    }
    meta[t] = make_float4(nrm2, rn, dot1, dot2);
}

// ---------------- lag-2 look-ahead gated rank-1 scan, 4row x 16col tiles --
// vp_t = A_t + c1*r_{t-1} + c2*r_{t-2},  A_t = (M_{t-3} k_t) * rn_t
// Thread (rowgrp=tid>>3, ch=tid&7) owns M[rowgrp*4..+4)[ch*16..+16).
// Per body: 9 ds_read_b128/thread (vs 32 before) -- LDS-pipe was the wall.
// Row-dots combine across 8 ch-lanes via 3 DPP hops (lane bits 0-2 = ch).
__global__ __launch_bounds__(256, 1)
void k_scan(const float* __restrict__ k_all, const float4* __restrict__ meta,
            float* __restrict__ readv)
{
    __shared__ float lds[8 * 136];      // 8-slot ring, row r in slot r&7, 128 f + pad
    __shared__ float4 part4[2];
    const int b = blockIdx.x, tid = threadIdx.x;
    const int rowgrp = tid >> 3, ch = tid & 7, lane = tid & 63, w = tid >> 6;
    const float* kb = k_all + (size_t)b * Lsz * Hsz;
    const float4* mb = meta + (size_t)b * Lsz;

    const int chunkoff = ch * 16;
    const int keloff = rowgrp * 4;

    f2v M2[32];                          // [row i][col pair j] = M2[i*8+j]
#pragma unroll
    for (int j = 0; j < 32; j++) M2[j] = f2v{0.f, 0.f};

    // ---- prologue: stage rows 0..4, preload rows 5,6, fill mvA(row1), kelA(row0)
    for (int t0 = 0; t0 < 5; t0++) {
        float2 v = *(const float2*)(kb + (size_t)t0 * Hsz + 2 * lane);
        *(float2*)(lds + t0 * 136 + 2 * lane) = v;
    }
    float2 kgA = *(const float2*)(kb + (size_t)5 * Hsz + 2 * lane);
    float2 kgB = *(const float2*)(kb + (size_t)6 * Hsz + 2 * lane);
    __syncthreads();
    float4 mvA[4], mvB[4], kelA, kelB;
    {
        const float4* p = (const float4*)(lds + 1 * 136 + chunkoff);
        mvA[0] = p[0]; mvA[1] = p[1]; mvA[2] = p[2]; mvA[3] = p[3];
    }
    kelA = *(const float4*)(lds + 0 * 136 + keloff);
    float4 m0 = mb[0], m1 = mb[1], m2 = mb[2];

    float4 a4 = {0, 0, 0, 0};
    float4 r1el = {0, 0, 0, 0}, r2el = {0, 0, 0, 0};
    float4 uc1 = {0, 0, 0, 0}, uc2 = {0, 0, 0, 0};
    float c1 = 0.f, c2 = 0.f, c2p = 0.f;
    bool g1 = false, g2 = false;

#define UPD_ROW(i, ucv) { f2v c = {ucv, ucv};                                   \
    M2[(i)*8+0]=pkfma(c,f2v{uT0.x,uT0.y},M2[(i)*8+0]);                          \
    M2[(i)*8+1]=pkfma(c,f2v{uT0.z,uT0.w},M2[(i)*8+1]);                          \
    M2[(i)*8+2]=pkfma(c,f2v{uT1.x,uT1.y},M2[(i)*8+2]);                          \
    M2[(i)*8+3]=pkfma(c,f2v{uT1.z,uT1.w},M2[(i)*8+3]);                          \
    M2[(i)*8+4]=pkfma(c,f2v{uT2.x,uT2.y},M2[(i)*8+4]);                          \
    M2[(i)*8+5]=pkfma(c,f2v{uT2.z,uT2.w},M2[(i)*8+5]);                          \
    M2[(i)*8+6]=pkfma(c,f2v{uT3.x,uT3.y},M2[(i)*8+6]);                          \
    M2[(i)*8+7]=pkfma(c,f2v{uT3.z,uT3.w},M2[(i)*8+7]); }

#define MV_ROW(i, dst, src) { f2v acc = {0.f, 0.f};                             \
    acc = pkfma(M2[(i)*8+0], f2v{src[0].x, src[0].y}, acc);                     \
    acc = pkfma(M2[(i)*8+1], f2v{src[0].z, src[0].w}, acc);                     \
    acc = pkfma(M2[(i)*8+2], f2v{src[1].x, src[1].y}, acc);                     \
    acc = pkfma(M2[(i)*8+3], f2v{src[1].z, src[1].w}, acc);                     \
    acc = pkfma(M2[(i)*8+4], f2v{src[2].x, src[2].y}, acc);                     \
    acc = pkfma(M2[(i)*8+5], f2v{src[2].z, src[2].w}, acc);                     \
    acc = pkfma(M2[(i)*8+6], f2v{src[3].x, src[3].y}, acc);                     \
    acc = pkfma(M2[(i)*8+7], f2v{src[3].z, src[3].w}, acc);                     \
    dst = acc.x + acc.y;                                                        \
    dst = dppadd<0xB1, 0xf>(dst);                                               \
    dst = dppadd<0x4E, 0xf>(dst);                                               \
    dst = dppadd<0x141, 0xf>(dst); }

    auto body = [&](int t, float4 (&mvUse)[4], float4 (&mvFill)[4],
                    float4& kelUse, float4& kelFill, float2& kgreg) {
        const int sW = (t + 5) & 7, sU = (t - 2) & 7, sMv = (t + 2) & 7, sK = (t + 1) & 7;
        const int slot = t & 1;

        // issue LDS reads: update chunk (row t-2), next matvec chunk (row t+2), kel (row t+1)
        float4 uT0, uT1, uT2, uT3;
        {
            const float4* p = (const float4*)(lds + sU * 136 + chunkoff);
            uT0 = p[0]; uT1 = p[1]; uT2 = p[2]; uT3 = p[3];
        }
        {
            const float4* p = (const float4*)(lds + sMv * 136 + chunkoff);
            mvFill[0] = p[0]; mvFill[1] = p[1]; mvFill[2] = p[2]; mvFill[3] = p[3];
        }
        kelFill = *(const float4*)(lds + sK * 136 + keloff);

        // ---- gate chain: residual (4 rows) + DPP wave reduce ----
        float4 rel;
        rel.x = fmaf(-c2, r2el.x, fmaf(-c1, r1el.x, kelUse.x - a4.x));
        rel.y = fmaf(-c2, r2el.y, fmaf(-c1, r1el.y, kelUse.y - a4.y));
        rel.z = fmaf(-c2, r2el.z, fmaf(-c1, r1el.z, kelUse.z - a4.z));
        rel.w = fmaf(-c2, r2el.w, fmaf(-c1, r1el.w, kelUse.w - a4.w));
        float s = fmaf(rel.w, rel.w, fmaf(rel.z, rel.z, fmaf(rel.y, rel.y, rel.x * rel.x)));
        s = dppadd<0xB1, 0xf>(s);
        s = dppadd<0x4E, 0xf>(s);
        s = dppadd<0x141, 0xf>(s);
        s = dppadd<0x140, 0xf>(s);
        s = dppadd<0x142, 0xa>(s);
        s = dppadd<0x143, 0xc>(s);
        if (lane == 63) ((float*)&part4[slot])[w] = s;

        // ---- stage row t+5, prefetch row t+7 ----
        *(float2*)(lds + sW * 136 + 2 * lane) = kgreg;
        {
            int tl = t + 7; if (tl > Lsz - 1) tl = Lsz - 1;
            kgreg = *(const float2*)(kb + (size_t)tl * Hsz + 2 * lane);
        }

        // ---- lagged rank-1 update u_{t-2} ----
        if (g2) {
            UPD_ROW(0, uc2.x); UPD_ROW(1, uc2.y); UPD_ROW(2, uc2.z); UPD_ROW(3, uc2.w);
        }
        // ---- matvec partials A_{t+1} = M_{t-2} k_{t+1}, combine over ch ----
        float4 an4;
        MV_ROW(0, an4.x, mvUse); MV_ROW(1, an4.y, mvUse);
        MV_ROW(2, an4.z, mvUse); MV_ROW(3, an4.w, mvUse);

        __syncthreads();
        float4 p = part4[slot];
        float4 m3;
        { int tm = t + 3; if (tm > Lsz - 1) tm = Lsz - 1; m3 = mb[tm]; }
        // 1/(16384*8): 8 ch-duplicates of each row residual in the wave sum
        float energy = (p.x + p.y + p.z + p.w) * 7.62939453125e-06f
                       * m0.x * m0.y * m0.y;
        bool g = energy >= 0.4f;             // block-uniform

        // ---- pipeline shifts ----
        a4.x = an4.x * m1.y; a4.y = an4.y * m1.y;
        a4.z = an4.z * m1.y; a4.w = an4.w * m1.y;
        c1 = g ? m0.z * m0.y * m1.y : 0.f;
        c2 = c2p;
        c2p = g ? m0.w * m0.y * m2.y : 0.f;
        uc2 = uc1;
        if (g) { uc1.x = rel.x * m0.y; uc1.y = rel.y * m0.y;
                 uc1.z = rel.z * m0.y; uc1.w = rel.w * m0.y; }
        else   { uc1 = float4{0, 0, 0, 0}; }
        g2 = g1; g1 = g;
        r2el = r1el; r1el = rel;
        m0 = m1; m1 = m2; m2 = m3;
    };

    for (int t = 0; t < Lsz - 2; t += 2) {   // bodies 0..2045
        body(t,     mvA, mvB, kelA, kelB, kgA);
        body(t + 1, mvB, mvA, kelB, kelA, kgB);
    }
    body(Lsz - 2, mvA, mvB, kelA, kelB, kgA);  // body 2046

    // ---- epilogue: pending u_2045 (uc2,g2, slot 5) and u_2046 (uc1,g1, slot 6)
    if (g2) {
        const float4* p = (const float4*)(lds + 5 * 136 + chunkoff);
        float4 uT0 = p[0], uT1 = p[1], uT2 = p[2], uT3 = p[3];
        UPD_ROW(0, uc2.x); UPD_ROW(1, uc2.y); UPD_ROW(2, uc2.z); UPD_ROW(3, uc2.w);
    }
    if (g1) {
        const float4* p = (const float4*)(lds + 6 * 136 + chunkoff);
        float4 uT0 = p[0], uT1 = p[1], uT2 = p[2], uT3 = p[3];
        UPD_ROW(0, uc1.x); UPD_ROW(1, uc1.y); UPD_ROW(2, uc1.z); UPD_ROW(3, uc1.w);
    }
    {   // read = M_2046 . q  (raw q = row 2047, slot 7)
        float4 qc[4];
        const float4* p = (const float4*)(lds + 7 * 136 + chunkoff);
        qc[0] = p[0]; qc[1] = p[1]; qc[2] = p[2]; qc[3] = p[3];
        float4 an4;
        MV_ROW(0, an4.x, qc); MV_ROW(1, an4.y, qc);
        MV_ROW(2, an4.z, qc); MV_ROW(3, an4.w, qc);
        if (ch == 0) *(float4*)(readv + b * Hsz + keloff) = an4;
    }
#undef UPD_ROW
#undef MV_ROW
}

// ---------------- r2T[n][b] = read[b] @ rp_w.T + rp_b -----------------
__global__ void k_r2(const float* __restrict__ readv, const float* __restrict__ rp_w,
                     const float* __restrict__ rp_b, float* __restrict__ r2T)
{
    int b = blockIdx.x, n = threadIdx.x;
    const float* rr = readv + b * Hsz;
    const float* wr = rp_w + (size_t)n * Hsz;
    float acc = rp_b[n];
    for (int k = 0; k < Hsz; k++) acc = fmaf(rr[k], wr[k], acc);
    r2T[(size_t)n * Bsz + b] = acc;
}

// ---------------- out[b][v] = r2[b] . out_w[v] + out_b[v] -----------------
__global__ __launch_bounds__(256, 4)
void k_out(const float* __restrict__ owT, const float* __restrict__ r2T,
           const float* __restrict__ outb, float* __restrict__ outp)
{
    int v = blockIdx.x * 256 + threadIdx.x;
    float ob = outb[v];
    float acc[Bsz];
#pragma unroll
    for (int b = 0; b < Bsz; b++) acc[b] = ob;
    for (int k = 0; k < Hsz; k++) {
        float wv = owT[(size_t)k * Vsz + v];
        const float* rr = r2T + k * Bsz;
#pragma unroll
        for (int b = 0; b < Bsz; b++) acc[b] = fmaf(wv, rr[b], acc[b]);
    }
#pragma unroll
    for (int b = 0; b < Bsz; b++) outp[(size_t)b * Vsz + v] = acc[b];
}

extern "C" void kernel_launch(void* const* d_in, const int* in_sizes, int n_in,
                              void* d_out, int out_size, void* d_ws, size_t ws_size,
                              hipStream_t stream)
{
    const int*   seq    = (const int*)  d_in[0];
    const float* embedW = (const float*)d_in[1];
    const float* ff_w1  = (const float*)d_in[2];
    const float* ff_b1  = (const float*)d_in[3];
    const float* ff_w2  = (const float*)d_in[4];
    const float* ff_b2  = (const float*)d_in[5];
    const float* ln_g   = (const float*)d_in[6];
    const float* ln_b   = (const float*)d_in[7];
    const float* kp_w   = (const float*)d_in[8];
    const float* rp_w   = (const float*)d_in[9];
    const float* rp_b   = (const float*)d_in[10];
    const float* out_w  = (const float*)d_in[11];
    const float* out_b  = (const float*)d_in[12];
    float* out = (float*)d_out;

    float* ws    = (float*)d_ws;
    float* k_all = ws;                                   // 16,777,216 f
    float* owT   = k_all + (size_t)TOK * Hsz;            //  4,096,000 f
    float* w1T   = owT   + (size_t)Hsz * Vsz;            // 32768
    float* w2T   = w1T   + 32768;                        // 32768
    float* kpT   = w2T   + 32768;                        // 16384
    float* norms = kpT   + 16384;                        // TOK
    float* metaf = norms + TOK;                          // 4*TOK (float4, 16B-aligned)
    float* readv = metaf + 4 * (size_t)TOK;              // B*H
    float* r2T   = readv + Bsz * Hsz;                    // H*B
    float4* meta = (float4*)metaf;

    k_tr<<<dim3(4, 8),    dim3(256), 0, stream>>>(ff_w1, w1T, 256, 128);
    k_tr<<<dim3(8, 4),    dim3(256), 0, stream>>>(ff_w2, w2T, 128, 256);
    k_tr<<<dim3(4, 4),    dim3(256), 0, stream>>>(kp_w,  kpT, 128, 128);
    k_tr<<<dim3(4, 1000), dim3(256), 0, stream>>>(out_w, owT, Vsz, 128);

    k_ff<<<dim3(TOK / 256), dim3(256), 0, stream>>>(
        seq, embedW, w1T, ff_b1, w2T, ff_b2, ln_g, ln_b, kpT, k_all, norms);

    k_meta<<<dim3(TOK / 256), dim3(256), 0, stream>>>(k_all, norms, meta);

    k_scan<<<dim3(Bsz), dim3(256), 0, stream>>>(k_all, meta, readv);

    k_r2<<<dim3(Bsz), dim3(128), 0, stream>>>(readv, rp_w, rp_b, r2T);

    k_out<<<dim3(Vsz / 256), dim3(256), 0, stream>>>(owT, r2T, out_b, out);
}

// Round 9
// 1538.379 us; speedup vs baseline: 1.2742x; 1.0971x over previous
//
#include <hip/hip_runtime.h>
#include <math.h>

constexpr int Bsz = 64;
constexpr int Lsz = 2048;
constexpr int Hsz = 128;
constexpr int Vsz = 32000;
constexpr int TOK = Bsz * Lsz;

typedef float f2v __attribute__((ext_vector_type(2)));

__device__ __forceinline__ f2v pkfma(f2v a, f2v b, f2v c) {
    return __builtin_elementwise_fma(a, b, c);
}

// ---------------- DPP add helper: v += dpp_move(v) --------------------------
template<int CTRL, int RM>
__device__ __forceinline__ float dppadd(float v) {
    int x = __builtin_amdgcn_update_dpp(0, __float_as_int(v), CTRL, RM, 0xf, false);
    return v + __int_as_float(x);
}

// ---------------- generic transpose: in[R][C] -> out[C][R] ----------------
__global__ void k_tr(const float* __restrict__ in, float* __restrict__ out, int R, int C) {
    __shared__ float tile[32][33];
    int bc = blockIdx.x * 32, br = blockIdx.y * 32;
    int tx = threadIdx.x & 31, ty = threadIdx.x >> 5;  // 256 threads
#pragma unroll
    for (int i = 0; i < 4; i++) {
        int r = br + ty + 8 * i, c = bc + tx;
        if (r < R && c < C) tile[ty + 8 * i][tx] = in[(size_t)r * C + c];
    }
    __syncthreads();
#pragma unroll
    for (int i = 0; i < 4; i++) {
        int c = bc + ty + 8 * i, r = br + tx;
        if (c < C && r < R) out[(size_t)c * R + r] = tile[tx][ty + 8 * i];
    }
}

// ---------------- fused embed + FF1 + FF2 + residual + LN + kp + norms ----
__global__ __launch_bounds__(256, 2)
void k_ff(const int* __restrict__ seq, const float* __restrict__ embed,
          const float* __restrict__ w1T, const float* __restrict__ b1,
          const float* __restrict__ w2T, const float* __restrict__ b2,
          const float* __restrict__ ln_g, const float* __restrict__ ln_b,
          const float* __restrict__ kpT,
          float* __restrict__ k_all, float* __restrict__ norms)
{
    __shared__ float su[256 * 65];
    const int tid = threadIdx.x;
    const int tok = blockIdx.x * 256 + tid;
    const float* hrow = embed + (size_t)seq[tok] * Hsz;
    float* myl = su + tid * 65;

    float f[Hsz];
#pragma unroll
    for (int n = 0; n < Hsz; n++) f[n] = b2[n];

    for (int p = 0; p < 4; p++) {
        float u[64];
#pragma unroll
        for (int n = 0; n < 64; n++) u[n] = b1[p * 64 + n];
        const float* w1p = w1T + p * 64;
        for (int k = 0; k < Hsz; k += 4) {
            float4 a = *(const float4*)(hrow + k);
            const float* wr = w1p + (size_t)k * 256;
#pragma unroll
            for (int n = 0; n < 64; n++) u[n] = fmaf(a.x, wr[n], u[n]);
            wr += 256;
#pragma unroll
            for (int n = 0; n < 64; n++) u[n] = fmaf(a.y, wr[n], u[n]);
            wr += 256;
#pragma unroll
            for (int n = 0; n < 64; n++) u[n] = fmaf(a.z, wr[n], u[n]);
            wr += 256;
#pragma unroll
            for (int n = 0; n < 64; n++) u[n] = fmaf(a.w, wr[n], u[n]);
        }
#pragma unroll
        for (int n = 0; n < 64; n++) myl[n] = fmaxf(u[n], 0.0f);
        const float* w2p = w2T + (size_t)(p * 64) * Hsz;
        for (int kk = 0; kk < 64; kk++) {
            float uv = myl[kk];
            const float* wr = w2p + (size_t)kk * Hsz;
#pragma unroll
            for (int n = 0; n < Hsz; n++) f[n] = fmaf(uv, wr[n], f[n]);
        }
    }

    float m0 = 0, m1 = 0, m2 = 0, m3 = 0;
#pragma unroll
    for (int n = 0; n < Hsz; n += 4) {
        float4 hv = *(const float4*)(hrow + n);
        f[n] += hv.x; f[n + 1] += hv.y; f[n + 2] += hv.z; f[n + 3] += hv.w;
        m0 += f[n]; m1 += f[n + 1]; m2 += f[n + 2]; m3 += f[n + 3];
    }
    float mu = (m0 + m1 + m2 + m3) * (1.0f / Hsz);
    float v0 = 0, v1 = 0, v2 = 0, v3 = 0;
#pragma unroll
    for (int n = 0; n < Hsz; n += 4) {
        float d0 = f[n] - mu, d1 = f[n + 1] - mu, d2 = f[n + 2] - mu, d3 = f[n + 3] - mu;
        v0 = fmaf(d0, d0, v0); v1 = fmaf(d1, d1, v1);
        v2 = fmaf(d2, d2, v2); v3 = fmaf(d3, d3, v3);
    }
    float var = (v0 + v1 + v2 + v3) * (1.0f / Hsz);
    float rs = 1.0f / sqrtf(var + 1e-5f);
#pragma unroll
    for (int n = 0; n < Hsz; n++) f[n] = (f[n] - mu) * rs * ln_g[n] + ln_b[n];

    float nrm2 = 0.0f;
    float* kout = k_all + (size_t)tok * Hsz;
    for (int p2 = 0; p2 < 2; p2++) {
        float acc[64];
#pragma unroll
        for (int n = 0; n < 64; n++) acc[n] = 0.0f;
        for (int kh = 0; kh < 2; kh++) {
#pragma unroll
            for (int n = 0; n < 64; n++) myl[n] = f[kh * 64 + n];
            const float* kpp = kpT + (size_t)(kh * 64) * Hsz + p2 * 64;
            for (int k = 0; k < 64; k++) {
                float yv = myl[k];
                const float* wr = kpp + (size_t)k * Hsz;
#pragma unroll
                for (int n = 0; n < 64; n++) acc[n] = fmaf(yv, wr[n], acc[n]);
            }
        }
#pragma unroll
        for (int n = 0; n < 64; n++) nrm2 = fmaf(acc[n], acc[n], nrm2);
#pragma unroll
        for (int n = 0; n < 64; n += 4) {
            float4 vv; vv.x = acc[n]; vv.y = acc[n + 1]; vv.z = acc[n + 2]; vv.w = acc[n + 3];
            *(float4*)(kout + p2 * 64 + n) = vv;
        }
    }
    norms[tok] = nrm2;
}

// ------- per-row meta: {nrm2, rn, dot(k_t,k_t+1), unused} -----------------
__global__ void k_meta(const float* __restrict__ k_all, const float* __restrict__ norms,
                       float4* __restrict__ meta)
{
    int t = blockIdx.x * 256 + threadIdx.x;   // 0..TOK-1
    int i = t & (Lsz - 1);
    float nrm2 = norms[t];
    float rn = 1.0f / fmaxf(sqrtf(nrm2), 1e-12f);
    float dot1 = 0.f;
    const float4* r0 = (const float4*)(k_all + (size_t)t * Hsz);
    if (i < Lsz - 1) {
        const float4* r1 = (const float4*)(k_all + (size_t)(t + 1) * Hsz);
        float d0 = 0, d1 = 0, d2 = 0, d3 = 0;
#pragma unroll
        for (int q = 0; q < 32; q++) {
            float4 x = r0[q], y = r1[q];
            d0 = fmaf(x.x, y.x, d0); d1 = fmaf(x.y, y.y, d1);
            d2 = fmaf(x.z, y.z, d2); d3 = fmaf(x.w, y.w, d3);
        }
        dot1 = (d0 + d1) + (d2 + d3);
    }
    meta[t] = make_float4(nrm2, rn, dot1, 0.f);
}

// ---------------- lag-1 gated rank-1 scan, 4row x 16col tiles, reg ring ---
// vp_t = A_t + c1*r_{t-1};  A_t = (M_{t-2} k_t)*rn_t; update u_{t-1} applied
// at body t BEFORE matvec (gate resolved at end of body t-1) -> M_{t-1}.
// Chunk ch of each row at LDS float offset ch*20 (80B) -> ds_read_b128 i of
// chunk ch hits bank-quad (5ch+i)%8: all 8 ch distinct, conflict-free.
// Register ring R0..R3 (row r in slot r&3) removes the update's LDS re-read:
// 5 ds_read_b128/thread/body (was 9), 4-body unroll keeps indices static.
__global__ __launch_bounds__(256, 1)
void k_scan(const float* __restrict__ k_all, const float4* __restrict__ meta,
            float* __restrict__ readv)
{
    __shared__ float lds[8 * 160];      // 8-slot ring of swizzled k rows
    __shared__ float4 part4[2];
    const int b = blockIdx.x, tid = threadIdx.x;
    const int rowgrp = tid >> 3, ch = tid & 7, lane = tid & 63, w = tid >> 6;
    const float* kb = k_all + (size_t)b * Lsz * Hsz;
    const float4* mb = meta + (size_t)b * Lsz;

    const int chunkf = ch * 20;                                  // my chunk base (floats)
    const int kelf = (rowgrp >> 2) * 20 + ((rowgrp & 3) * 4);    // my 4 kel elems
    const int stf = ((2 * lane) >> 4) * 20 + ((2 * lane) & 15);  // stage-write offset

    f2v M2[32];                          // M[rowgrp*4+i][ch*16+2j] pairs: M2[i*8+j]
#pragma unroll
    for (int j = 0; j < 32; j++) M2[j] = f2v{0.f, 0.f};

    // ---- prologue: stage rows 0..4 (swizzled), preload rows 5,6 ----
    for (int t0 = 0; t0 < 5; t0++) {
        float2 v = *(const float2*)(kb + (size_t)t0 * Hsz + 2 * lane);
        *(float2*)(lds + t0 * 160 + stf) = v;
    }
    float2 kgA = *(const float2*)(kb + (size_t)5 * Hsz + 2 * lane);
    float2 kgB = *(const float2*)(kb + (size_t)6 * Hsz + 2 * lane);
    __syncthreads();

    float4 R0[4], R1[4], R2[4], R3[4];   // ring: row r chunk in R{r&3}
    {
        const float4* p = (const float4*)(lds + 0 * 160 + chunkf);
        R0[0] = p[0]; R0[1] = p[1]; R0[2] = p[2]; R0[3] = p[3];
    }
    {
        const float4* p = (const float4*)(lds + 1 * 160 + chunkf);
        R1[0] = p[0]; R1[1] = p[1]; R1[2] = p[2]; R1[3] = p[3];
    }
#pragma unroll
    for (int i = 0; i < 4; i++) { R2[i] = float4{0,0,0,0}; R3[i] = float4{0,0,0,0}; }
    float4 kelA = *(const float4*)(lds + 0 * 160 + kelf), kelB = {0,0,0,0};
    float4 m0 = mb[0], m1 = mb[1];

    float4 a4 = {0, 0, 0, 0}, r1el = {0, 0, 0, 0}, uc1 = {0, 0, 0, 0};
    float c1 = 0.f;
    bool g1 = false;

#define UPD_ROW(i, ucv, src) { f2v c = {ucv, ucv};                              \
    M2[(i)*8+0]=pkfma(c,f2v{src[0].x,src[0].y},M2[(i)*8+0]);                    \
    M2[(i)*8+1]=pkfma(c,f2v{src[0].z,src[0].w},M2[(i)*8+1]);                    \
    M2[(i)*8+2]=pkfma(c,f2v{src[1].x,src[1].y},M2[(i)*8+2]);                    \
    M2[(i)*8+3]=pkfma(c,f2v{src[1].z,src[1].w},M2[(i)*8+3]);                    \
    M2[(i)*8+4]=pkfma(c,f2v{src[2].x,src[2].y},M2[(i)*8+4]);                    \
    M2[(i)*8+5]=pkfma(c,f2v{src[2].z,src[2].w},M2[(i)*8+5]);                    \
    M2[(i)*8+6]=pkfma(c,f2v{src[3].x,src[3].y},M2[(i)*8+6]);                    \
    M2[(i)*8+7]=pkfma(c,f2v{src[3].z,src[3].w},M2[(i)*8+7]); }

#define MV_ROW(i, dst, src) { f2v acc = {0.f, 0.f};                             \
    acc = pkfma(M2[(i)*8+0], f2v{src[0].x, src[0].y}, acc);                     \
    acc = pkfma(M2[(i)*8+1], f2v{src[0].z, src[0].w}, acc);                     \
    acc = pkfma(M2[(i)*8+2], f2v{src[1].x, src[1].y}, acc);                     \
    acc = pkfma(M2[(i)*8+3], f2v{src[1].z, src[1].w}, acc);                     \
    acc = pkfma(M2[(i)*8+4], f2v{src[2].x, src[2].y}, acc);                     \
    acc = pkfma(M2[(i)*8+5], f2v{src[2].z, src[2].w}, acc);                     \
    acc = pkfma(M2[(i)*8+6], f2v{src[3].x, src[3].y}, acc);                     \
    acc = pkfma(M2[(i)*8+7], f2v{src[3].z, src[3].w}, acc);                     \
    dst = acc.x + acc.y;                                                        \
    dst = dppadd<0xB1, 0xf>(dst);                                               \
    dst = dppadd<0x4E, 0xf>(dst);                                               \
    dst = dppadd<0x141, 0xf>(dst); }

    auto body = [&](int t, float4 (&rUse)[4], float4 (&rFill)[4], float4 (&rUpd)[4],
                    float4& kelUse, float4& kelFill, float2& kgreg) {
        const int sW = (t + 5) & 7, sF = (t + 2) & 7, sK = (t + 1) & 7;
        const int slot = t & 1;

        // issue LDS reads: ring fill (row t+2), kel (row t+1)
        {
            const float4* p = (const float4*)(lds + sF * 160 + chunkf);
            rFill[0] = p[0]; rFill[1] = p[1]; rFill[2] = p[2]; rFill[3] = p[3];
        }
        kelFill = *(const float4*)(lds + sK * 160 + kelf);

        // ---- gate chain: residual (4 rows) + DPP wave reduce ----
        float4 rel;
        rel.x = fmaf(-c1, r1el.x, kelUse.x - a4.x);
        rel.y = fmaf(-c1, r1el.y, kelUse.y - a4.y);
        rel.z = fmaf(-c1, r1el.z, kelUse.z - a4.z);
        rel.w = fmaf(-c1, r1el.w, kelUse.w - a4.w);
        float s = fmaf(rel.w, rel.w, fmaf(rel.z, rel.z, fmaf(rel.y, rel.y, rel.x * rel.x)));
        s = dppadd<0xB1, 0xf>(s);
        s = dppadd<0x4E, 0xf>(s);
        s = dppadd<0x141, 0xf>(s);
        s = dppadd<0x140, 0xf>(s);
        s = dppadd<0x142, 0xa>(s);
        s = dppadd<0x143, 0xc>(s);
        if (lane == 63) ((float*)&part4[slot])[w] = s;

        // ---- stage row t+5 (swizzled), prefetch row t+7 ----
        *(float2*)(lds + sW * 160 + stf) = kgreg;
        {
            int tl = t + 7; if (tl > Lsz - 1) tl = Lsz - 1;
            kgreg = *(const float2*)(kb + (size_t)tl * Hsz + 2 * lane);
        }

        // ---- update u_{t-1} from register ring (gate resolved last body) ----
        if (g1) {
            UPD_ROW(0, uc1.x, rUpd); UPD_ROW(1, uc1.y, rUpd);
            UPD_ROW(2, uc1.z, rUpd); UPD_ROW(3, uc1.w, rUpd);
        }
        // ---- matvec A_{t+1} = M_{t-1} k_{t+1} ----
        float4 an4;
        MV_ROW(0, an4.x, rUse); MV_ROW(1, an4.y, rUse);
        MV_ROW(2, an4.z, rUse); MV_ROW(3, an4.w, rUse);

        __syncthreads();
        float4 p = part4[slot];
        float4 mnext;
        { int tm = t + 2; if (tm > Lsz - 1) tm = Lsz - 1; mnext = mb[tm]; }
        // 1/(16384*8): 8 ch-duplicates of each row residual in the wave sum
        float energy = (p.x + p.y + p.z + p.w) * 7.62939453125e-06f
                       * m0.x * m0.y * m0.y;
        bool g = energy >= 0.4f;             // block-uniform

        // ---- pipeline shifts ----
        a4.x = an4.x * m1.y; a4.y = an4.y * m1.y;
        a4.z = an4.z * m1.y; a4.w = an4.w * m1.y;
        c1 = g ? m0.z * m0.y * m1.y : 0.f;
        if (g) { uc1.x = rel.x * m0.y; uc1.y = rel.y * m0.y;
                 uc1.z = rel.z * m0.y; uc1.w = rel.w * m0.y; }
        else   { uc1 = float4{0, 0, 0, 0}; }
        g1 = g;
        r1el = rel;
        m0 = m1; m1 = mnext;
    };

    for (int t = 0; t < Lsz - 4; t += 4) {   // bodies 0..2043 (511 iters)
        body(t,     R1, R2, R3, kelA, kelB, kgA);
        body(t + 1, R2, R3, R0, kelB, kelA, kgB);
        body(t + 2, R3, R0, R1, kelA, kelB, kgA);
        body(t + 3, R0, R1, R2, kelB, kelA, kgB);
    }
    body(Lsz - 4, R1, R2, R3, kelA, kelB, kgA);  // body 2044
    body(Lsz - 3, R2, R3, R0, kelB, kelA, kgB);  // body 2045
    body(Lsz - 2, R3, R0, R1, kelA, kelB, kgA);  // body 2046

    // ---- epilogue: pending u_2046 (row 2046 = R2), then read = M . q (R3) --
    if (g1) {
        UPD_ROW(0, uc1.x, R2); UPD_ROW(1, uc1.y, R2);
        UPD_ROW(2, uc1.z, R2); UPD_ROW(3, uc1.w, R2);
    }
    {
        float4 an4;
        MV_ROW(0, an4.x, R3); MV_ROW(1, an4.y, R3);
        MV_ROW(2, an4.z, R3); MV_ROW(3, an4.w, R3);
        if (ch == 0) *(float4*)(readv + b * Hsz + rowgrp * 4) = an4;
    }
#undef UPD_ROW
#undef MV_ROW
}

// ---------------- r2T[n][b] = read[b] @ rp_w.T + rp_b -----------------
__global__ void k_r2(const float* __restrict__ readv, const float* __restrict__ rp_w,
                     const float* __restrict__ rp_b, float* __restrict__ r2T)
{
    int b = blockIdx.x, n = threadIdx.x;
    const float* rr = readv + b * Hsz;
    const float* wr = rp_w + (size_t)n * Hsz;
    float acc = rp_b[n];
    for (int k = 0; k < Hsz; k++) acc = fmaf(rr[k], wr[k], acc);
    r2T[(size_t)n * Bsz + b] = acc;
}

// ---------------- out[b][v] = r2[b] . out_w[v] + out_b[v] -----------------
__global__ __launch_bounds__(256, 4)
void k_out(const float* __restrict__ owT, const float* __restrict__ r2T,
           const float* __restrict__ outb, float* __restrict__ outp)
{
    int v = blockIdx.x * 256 + threadIdx.x;
    float ob = outb[v];
    float acc[Bsz];
#pragma unroll
    for (int b = 0; b < Bsz; b++) acc[b] = ob;
    for (int k = 0; k < Hsz; k++) {
        float wv = owT[(size_t)k * Vsz + v];
        const float* rr = r2T + k * Bsz;
#pragma unroll
        for (int b = 0; b < Bsz; b++) acc[b] = fmaf(wv, rr[b], acc[b]);
    }
#pragma unroll
    for (int b = 0; b < Bsz; b++) outp[(size_t)b * Vsz + v] = acc[b];
}

extern "C" void kernel_launch(void* const* d_in, const int* in_sizes, int n_in,
                              void* d_out, int out_size, void* d_ws, size_t ws_size,
                              hipStream_t stream)
{
    const int*   seq    = (const int*)  d_in[0];
    const float* embedW = (const float*)d_in[1];
    const float* ff_w1  = (const float*)d_in[2];
    const float* ff_b1  = (const float*)d_in[3];
    const float* ff_w2  = (const float*)d_in[4];
    const float* ff_b2  = (const float*)d_in[5];
    const float* ln_g   = (const float*)d_in[6];
    const float* ln_b   = (const float*)d_in[7];
    const float* kp_w   = (const float*)d_in[8];
    const float* rp_w   = (const float*)d_in[9];
    const float* rp_b   = (const float*)d_in[10];
    const float* out_w  = (const float*)d_in[11];
    const float* out_b  = (const float*)d_in[12];
    float* out = (float*)d_out;

    float* ws    = (float*)d_ws;
    float* k_all = ws;                                   // 16,777,216 f
    float* owT   = k_all + (size_t)TOK * Hsz;            //  4,096,000 f
    float* w1T   = owT   + (size_t)Hsz * Vsz;            // 32768
    float* w2T   = w1T   + 32768;                        // 32768
    float* kpT   = w2T   + 32768;                        // 16384
    float* norms = kpT   + 16384;                        // TOK
    float* metaf = norms + TOK;                          // 4*TOK (float4, 16B-aligned)
    float* readv = metaf + 4 * (size_t)TOK;              // B*H
    float* r2T   = readv + Bsz * Hsz;                    // H*B
    float4* meta = (float4*)metaf;

    k_tr<<<dim3(4, 8),    dim3(256), 0, stream>>>(ff_w1, w1T, 256, 128);
    k_tr<<<dim3(8, 4),    dim3(256), 0, stream>>>(ff_w2, w2T, 128, 256);
    k_tr<<<dim3(4, 4),    dim3(256), 0, stream>>>(kp_w,  kpT, 128, 128);
    k_tr<<<dim3(4, 1000), dim3(256), 0, stream>>>(out_w, owT, Vsz, 128);

    k_ff<<<dim3(TOK / 256), dim3(256), 0, stream>>>(
        seq, embedW, w1T, ff_b1, w2T, ff_b2, ln_g, ln_b, kpT, k_all, norms);

    k_meta<<<dim3(TOK / 256), dim3(256), 0, stream>>>(k_all, norms, meta);

    k_scan<<<dim3(Bsz), dim3(256), 0, stream>>>(k_all, meta, readv);

    k_r2<<<dim3(Bsz), dim3(128), 0, stream>>>(readv, rp_w, rp_b, r2T);

    k_out<<<dim3(Vsz / 256), dim3(256), 0, stream>>>(owT, r2T, out_b, out);
}